// Round 7
// baseline (169.258 us; speedup 1.0000x reference)
//
#include <hip/hip_runtime.h>
#include <math.h>

// HadamardProj: out[b,o] = -scale * (x[b]/(||x[b]||+eps)) . H[o,:] + bias[o]
// H[o,i] = (-1)^popcount(o&i), i<2048  =>  H row o == H row (o mod 2048)
// => y[b] = FWHT_2048(x[b]) (Sylvester), out[b,o] = -scale*inv_norm*y[o&2047] + bias[o]
//
// R7: per-wave software pipeline over 4 rows — prefetch row r+1's x before
// computing row r, so HBM latency hides under FWHT+stores and the CU memory
// port never idles during the compute phase (R1..R6 all convoyed at 165 us).

typedef float f32x4 __attribute__((ext_vector_type(4)));

constexpr int N_IN  = 2048;    // 2^11
constexpr int N_OUT = 10000;
constexpr int WAVES_PER_BLOCK = 4;
constexpr int ROWS_PER_WAVE   = 4;

__global__ __launch_bounds__(256, 4) void fwht_proj_kernel(
    const float* __restrict__ x,
    const float* __restrict__ scale,
    const float* __restrict__ bias,
    float* __restrict__ out)
{
    __shared__ f32x4 biaslds[N_OUT / 4];   // 40,000 B -> 4 blocks/CU

    // Stage bias once per block (amortized over 16 rows)
    {
        const f32x4* __restrict__ b4 = reinterpret_cast<const f32x4*>(bias);
        for (int i = threadIdx.x; i < N_OUT / 4; i += 256)
            biaslds[i] = b4[i];
    }
    __syncthreads();

    const int wave = threadIdx.x >> 6;
    const int lane = threadIdx.x & 63;
    // wave handles rows [wrow0 .. wrow0+3]
    const size_t wrow0 = ((size_t)blockIdx.x * WAVES_PER_BLOCK + wave) * ROWS_PER_WAVE;
    const float sc = scale[0];

    f32x4 cur[8], nxt[8];
    {
        const float* __restrict__ xr = x + wrow0 * N_IN;
#pragma unroll
        for (int j = 0; j < 8; ++j)
            cur[j] = *reinterpret_cast<const f32x4*>(xr + (j << 8) + (lane << 2));
    }

#pragma unroll
    for (int r = 0; r < ROWS_PER_WAVE; ++r) {
        // Prefetch next row's x before touching cur (hides HBM latency under
        // this row's FWHT + stores; compiler emits counted vmcnt for cur use).
        if (r + 1 < ROWS_PER_WAVE) {
            const float* __restrict__ xr = x + (wrow0 + r + 1) * N_IN;
#pragma unroll
            for (int j = 0; j < 8; ++j)
                nxt[j] = *reinterpret_cast<const f32x4*>(xr + (j << 8) + (lane << 2));
        }

        // ---- norm ----
        float ss = 0.0f;
#pragma unroll
        for (int j = 0; j < 8; ++j) {
            ss = fmaf(cur[j].x, cur[j].x, ss);
            ss = fmaf(cur[j].y, cur[j].y, ss);
            ss = fmaf(cur[j].z, cur[j].z, ss);
            ss = fmaf(cur[j].w, cur[j].w, ss);
        }
#pragma unroll
        for (int m = 1; m < 64; m <<= 1)
            ss += __shfl_xor(ss, m, 64);
        const float inv = 1.0f / (sqrtf(ss) + 1e-8f);   // matches x/(norm+eps)

        // ---- FWHT: stages h=1,2 inside float4 ----
#pragma unroll
        for (int j = 0; j < 8; ++j) {
            const f32x4 a = cur[j];
            f32x4 t;
            t.x = a.x + a.y;  t.y = a.x - a.y;
            t.z = a.z + a.w;  t.w = a.z - a.w;
            f32x4 u;
            u.x = t.x + t.z;  u.y = t.y + t.w;
            u.z = t.x - t.z;  u.w = t.y - t.w;
            cur[j] = u;
        }
        // ---- stages h=4..128: cross-lane (lane xor 1..32) ----
#pragma unroll
        for (int m = 1; m <= 32; m <<= 1) {
            const bool lo = (lane & m) == 0;
#pragma unroll
            for (int j = 0; j < 8; ++j) {
                f32x4 o;
                o.x = __shfl_xor(cur[j].x, m, 64);
                o.y = __shfl_xor(cur[j].y, m, 64);
                o.z = __shfl_xor(cur[j].z, m, 64);
                o.w = __shfl_xor(cur[j].w, m, 64);
                cur[j] = lo ? (cur[j] + o) : (o - cur[j]);
            }
        }
        // ---- stages h=256,512,1024: register index xor 1,2,4 ----
#pragma unroll
        for (int jm = 1; jm <= 4; jm <<= 1) {
#pragma unroll
            for (int j = 0; j < 8; ++j) {
                if ((j & jm) == 0) {
                    const f32x4 a = cur[j], b = cur[j ^ jm];
                    cur[j]      = a + b;
                    cur[j ^ jm] = a - b;
                }
            }
        }

        // ---- epilogue: register-resident, bias from LDS ----
        const float s = -sc * inv;
        float* __restrict__ orow = out + (wrow0 + r) * N_OUT;
#pragma unroll
        for (int w = 0; w < 4; ++w) {
#pragma unroll 4
            for (int j = 0; j < 8; ++j) {
                const int o = (w << 11) + (j << 8) + (lane << 2);
                const f32x4 b = biaslds[(w << 9) + (j << 6) + lane];
                f32x4 rv;
                rv.x = fmaf(s, cur[j].x, b.x);
                rv.y = fmaf(s, cur[j].y, b.y);
                rv.z = fmaf(s, cur[j].z, b.z);
                rv.w = fmaf(s, cur[j].w, b.w);
                *reinterpret_cast<f32x4*>(orow + o) = rv;
            }
        }
        // partial window w=4: j=0..6 full, j=7 lanes 0..3
#pragma unroll 4
        for (int j = 0; j < 7; ++j) {
            const int o = 8192 + (j << 8) + (lane << 2);
            const f32x4 b = biaslds[2048 + (j << 6) + lane];
            f32x4 rv;
            rv.x = fmaf(s, cur[j].x, b.x);
            rv.y = fmaf(s, cur[j].y, b.y);
            rv.z = fmaf(s, cur[j].z, b.z);
            rv.w = fmaf(s, cur[j].w, b.w);
            *reinterpret_cast<f32x4*>(orow + o) = rv;
        }
        if (lane < 4) {
            const int o = 9984 + (lane << 2);
            const f32x4 b = biaslds[2496 + lane];
            f32x4 rv;
            rv.x = fmaf(s, cur[7].x, b.x);
            rv.y = fmaf(s, cur[7].y, b.y);
            rv.z = fmaf(s, cur[7].z, b.z);
            rv.w = fmaf(s, cur[7].w, b.w);
            *reinterpret_cast<f32x4*>(orow + o) = rv;
        }

        // rotate pipeline (renamed away after full unroll)
        if (r + 1 < ROWS_PER_WAVE) {
#pragma unroll
            for (int j = 0; j < 8; ++j)
                cur[j] = nxt[j];
        }
    }
}

extern "C" void kernel_launch(void* const* d_in, const int* in_sizes, int n_in,
                              void* d_out, int out_size, void* d_ws, size_t ws_size,
                              hipStream_t stream) {
    const float* x     = (const float*)d_in[0];
    // d_in[1] = proj: unused — Hadamard structure computed via FWHT
    const float* scale = (const float*)d_in[2];
    const float* bias  = (const float*)d_in[3];
    float* out = (float*)d_out;

    const int rows = in_sizes[0] / N_IN;            // 16384
    dim3 grid(rows / (WAVES_PER_BLOCK * ROWS_PER_WAVE)), block(256);  // 1024
    hipLaunchKernelGGL(fwht_proj_kernel, grid, block, 0, stream,
                       x, scale, bias, out);
}